// Round 5
// baseline (428.936 us; speedup 1.0000x reference)
//
#include <hip/hip_runtime.h>
#include <cstdint>
#include <cstddef>

typedef unsigned short u16;
typedef __bf16 bf16x8 __attribute__((ext_vector_type(8)));
typedef float f32x4 __attribute__((ext_vector_type(4)));
typedef u16 u16x8 __attribute__((ext_vector_type(8)));
typedef u16 u16x4 __attribute__((ext_vector_type(4)));

#define NB 4
#define NN 4096
#define ND 1024
#define NH 16
#define NTOK (NB * NN)   // 16384

__device__ __forceinline__ u16 f2bf(float f) {
    unsigned u = __float_as_uint(f);
    u += 0x7fffu + ((u >> 16) & 1u);
    return (u16)(u >> 16);
}

__device__ __forceinline__ void gload_lds16(const void* g, void* l) {
    __builtin_amdgcn_global_load_lds(
        (const __attribute__((address_space(1))) void*)g,
        (__attribute__((address_space(3))) void*)l, 16, 0, 0);
}

// ---------------------------------------------------------------------------
// prep: cast x (fp32->bf16) and Wq|Wk|Wv|Wo into one bf16 weight block
// ---------------------------------------------------------------------------
__global__ __launch_bounds__(256) void prep_cast(
    const float* __restrict__ x,
    const float* __restrict__ wq, const float* __restrict__ wk,
    const float* __restrict__ wv, const float* __restrict__ wo,
    u16* __restrict__ xb, u16* __restrict__ wb)
{
    const int n_x4 = (NTOK * ND) / 4;       // 4194304
    const int n_w4 = (ND * ND) / 4;         // 262144 per weight (pow2 -> shifts)
    const int total = n_x4 + 4 * n_w4;      // 5242880
    for (int i = blockIdx.x * blockDim.x + threadIdx.x; i < total;
         i += gridDim.x * blockDim.x) {
        float4 v;
        u16* dst;
        if (i < n_x4) {
            v = ((const float4*)x)[i];
            dst = xb + (size_t)i * 4;
        } else {
            int j = i - n_x4;
            int w = j / n_w4;
            int off = j - w * n_w4;
            const float* src = (w == 0) ? wq : (w == 1) ? wk : (w == 2) ? wv : wo;
            v = ((const float4*)src)[off];
            dst = wb + (size_t)j * 4;
        }
        u16x4 o;
        o[0] = f2bf(v.x); o[1] = f2bf(v.y); o[2] = f2bf(v.z); o[3] = f2bf(v.w);
        *(u16x4*)dst = o;
    }
}

// ---------------------------------------------------------------------------
// gemm_bt: C[m][n] = sum_k A[m][k]*B[n][k], bf16 MFMA.  (round-2 PROVEN: 974 TF)
// Block 256x128, BK=64, 4 waves, wave tile 128x64 (acc 128 VGPR).
// 2 barriers/K-step, unbroken 64-MFMA region (compiler schedules fine-grained
// lgkmcnt), 2-3 blocks/CU give implicit cross-block overlap. Deep pipelining
// attempts (r1 coarse phase-split 790 TF, r3 4-chunk ring 845 TF) both lost
// to this -- do not re-introduce per-phase barriers/fences.
// XCD-aware bijective block remap (T1): FETCH 144->94 MB measured.
// LDS rows are 8 chunks of 16B; chunk c of row r stored at c^(r&7) (bank
// swizzle). gload source lane-map permuted to match. Zero bank conflicts
// (measured SQ_LDS_BANK_CONFLICT=0).
// ---------------------------------------------------------------------------
template <int OUT_MODE>
__global__ __launch_bounds__(256, 2) void gemm_bt(
    const u16* __restrict__ A, int lda,
    const u16* __restrict__ Bw, int ldb,
    void* __restrict__ Cout, int ldc, int K,
    const float* __restrict__ bias, const float* __restrict__ resid,
    int rows_per_batch, size_t b_stride)
{
    __shared__ alignas(16) u16 lA[256 * 64];   // 32 KB
    __shared__ alignas(16) u16 lB[128 * 64];   // 16 KB

    const int tid = threadIdx.x;
    const int wv = tid >> 6, lane = tid & 63;
    const int quad = lane >> 4, lrow = lane & 15;

    // XCD-aware bijective remap (nwg % 8 == 0)
    const int orig = blockIdx.y * gridDim.x + blockIdx.x;
    const int cpx = (gridDim.x * gridDim.y) >> 3;
    const int wgid = (orig & 7) * cpx + (orig >> 3);
    const int bx = wgid % gridDim.x;
    const int by = wgid / gridDim.x;

    const int row0 = by * 256, col0 = bx * 128;
    const int wm = (wv >> 1) * 128, wn = (wv & 1) * 64;

    const u16* Bp = Bw + (b_stride ? (size_t)(row0 / rows_per_batch) * b_stride : 0);

    f32x4 acc[8][4] = {};

    const int srow = lane >> 3;                    // 0..7 (local row in 8-row seg)
    const int cswE = ((lane & 7) ^ srow) * 8;      // swizzled src col, elements

    for (int k0 = 0; k0 < K; k0 += 64) {
        __syncthreads();
#pragma unroll
        for (int i = 0; i < 8; ++i) {
            int rb = wv * 64 + i * 8;
            gload_lds16(A + (size_t)(row0 + rb + srow) * lda + k0 + cswE,
                        &lA[rb * 64]);
        }
#pragma unroll
        for (int i = 0; i < 4; ++i) {
            int rb = wv * 32 + i * 8;
            gload_lds16(Bp + (size_t)(col0 + rb + srow) * ldb + k0 + cswE,
                        &lB[rb * 64]);
        }
        __syncthreads();

#pragma unroll
        for (int kc = 0; kc < 2; ++kc) {
            const int ch = ((kc * 4 + quad) ^ (lrow & 7)) * 8;
            bf16x8 bfv[4];
#pragma unroll
            for (int t = 0; t < 4; ++t)
                bfv[t] = *(const bf16x8*)&lB[(wn + t * 16 + lrow) * 64 + ch];
#pragma unroll
            for (int mt = 0; mt < 8; ++mt) {
                bf16x8 af = *(const bf16x8*)&lA[(wm + mt * 16 + lrow) * 64 + ch];
#pragma unroll
                for (int nt = 0; nt < 4; ++nt)
                    acc[mt][nt] = __builtin_amdgcn_mfma_f32_16x16x32_bf16(
                        af, bfv[nt], acc[mt][nt], 0, 0, 0);
            }
        }
    }

    // epilogue; C/D layout: col = lane&15, row = quad*4 + reg
    float bvals[4];
    if (OUT_MODE == 1) {
#pragma unroll
        for (int nt = 0; nt < 4; ++nt)
            bvals[nt] = bias[col0 + wn + nt * 16 + lrow];
    }
#pragma unroll
    for (int mt = 0; mt < 8; ++mt)
#pragma unroll
        for (int nt = 0; nt < 4; ++nt)
#pragma unroll
            for (int r = 0; r < 4; ++r) {
                int grow = row0 + wm + mt * 16 + quad * 4 + r;
                int gcol = col0 + wn + nt * 16 + lrow;
                if (OUT_MODE == 0) {
                    ((u16*)Cout)[(size_t)grow * ldc + gcol] = f2bf(acc[mt][nt][r]);
                } else {
                    float vv = acc[mt][nt][r] + bvals[nt] +
                               resid[(size_t)grow * ldc + gcol];
                    ((float*)Cout)[(size_t)grow * ldc + gcol] = vv;
                }
            }
}

// ---------------------------------------------------------------------------
// gemm2_ln: fused  out = LayerNorm(q @ M_b^T + bo + x).
// Block = 32 rows x ALL 1024 cols (LN rows block-local). 256 threads, 4 waves
// (wave = 32 rows x 64 cols per 256-col chunk). Col-chunks nc=0..3; per
// (nc,k0) stage A[32][64] (4KB) + B[256][64] (32KB) single-buffered -- same
// proven staging/swizzle/fragment patterns as gemm_bt. acc[4][2][4] = 128
// VGPR. Epilogue: +bo +resid (f32), row stats via 16-lane shuffle butterfly
// + cross-wave LDS reduce, normalize, write out f32. Saves the y roundtrip
// (128 MB) + one launch vs gemm2 + ln; LN math identical (all f32).
// T1 remap: XCD k gets rows [k*2048,(k+1)*2048) -> one Mb batch panel (2MB)
// L2-resident per XCD.
// ---------------------------------------------------------------------------
__global__ __launch_bounds__(256, 3) void gemm2_ln(
    const u16* __restrict__ A,      // qkv [16384][3072], q = cols 0..1023
    const u16* __restrict__ Mball,  // [4][1024][1024] bf16
    const float* __restrict__ bias, // bo [1024]
    const float* __restrict__ resid,// x   [16384][1024] f32
    const float* __restrict__ gamma,
    const float* __restrict__ beta,
    float* __restrict__ out)        // [16384][1024] f32
{
    __shared__ alignas(16) u16 lA[32 * 64];    //  4 KB
    __shared__ alignas(16) u16 lB[256 * 64];   // 32 KB
    __shared__ float red[4][32][2];            //  1 KB

    const int tid = threadIdx.x;
    const int wv = tid >> 6, lane = tid & 63;
    const int quad = lane >> 4, lrow = lane & 15;

    // T1 bijective remap over 512 blocks (512 % 8 == 0)
    const int orig = blockIdx.x;
    const int wgid = (orig & 7) * 64 + (orig >> 3);
    const int row0 = wgid * 32;
    const u16* Bp = Mball + (size_t)(row0 >> 12) * ND * ND;

    const int srow = lane >> 3;
    const int cswE = ((lane & 7) ^ srow) * 8;

    f32x4 acc[4][2][4] = {};   // [nc][mt][nt]

#pragma unroll
    for (int nc = 0; nc < 4; ++nc) {
        const int ncol0 = nc * 256;
#pragma unroll 1
        for (int k0 = 0; k0 < 1024; k0 += 64) {
            __syncthreads();
            // A: 1 gload/wave (8 rows x 128B); rows 0..31 across 4 waves
            gload_lds16(A + (size_t)(row0 + wv * 8 + srow) * 3072 + k0 + cswE,
                        &lA[(wv * 8) * 64]);
            // B: 8 gloads/wave; B-rows ncol0..ncol0+255
#pragma unroll
            for (int i = 0; i < 8; ++i) {
                int rb = wv * 64 + i * 8;
                gload_lds16(Bp + (size_t)(ncol0 + rb + srow) * ND + k0 + cswE,
                            &lB[rb * 64]);
            }
            __syncthreads();
#pragma unroll
            for (int kc = 0; kc < 2; ++kc) {
                const int ch = ((kc * 4 + quad) ^ (lrow & 7)) * 8;
                bf16x8 bfv[4];
#pragma unroll
                for (int nt = 0; nt < 4; ++nt)
                    bfv[nt] = *(const bf16x8*)&lB[(wv * 64 + nt * 16 + lrow) * 64 + ch];
#pragma unroll
                for (int mt = 0; mt < 2; ++mt) {
                    bf16x8 af = *(const bf16x8*)&lA[(mt * 16 + lrow) * 64 + ch];
#pragma unroll
                    for (int nt = 0; nt < 4; ++nt)
                        acc[nc][mt][nt] = __builtin_amdgcn_mfma_f32_16x16x32_bf16(
                            af, bfv[nt], acc[nc][mt][nt], 0, 0, 0);
                }
            }
        }
    }

    // ---- epilogue: y = acc + bo + resid; LN over each row's 1024 cols ----
    // thread rows: rl = mt*16 + quad*4 + rr (8 rows); cols: nc*256+wv*64+nt*16+lrow
    float s8[2][4] = {{0.f, 0.f, 0.f, 0.f}, {0.f, 0.f, 0.f, 0.f}};
    float q8[2][4] = {{0.f, 0.f, 0.f, 0.f}, {0.f, 0.f, 0.f, 0.f}};
#pragma unroll
    for (int nc = 0; nc < 4; ++nc)
#pragma unroll
        for (int mt = 0; mt < 2; ++mt)
#pragma unroll
            for (int nt = 0; nt < 4; ++nt) {
                const int gcol = nc * 256 + wv * 64 + nt * 16 + lrow;
                const float bv = bias[gcol];
#pragma unroll
                for (int rr = 0; rr < 4; ++rr) {
                    const int grow = row0 + mt * 16 + quad * 4 + rr;
                    float v = acc[nc][mt][nt][rr] + bv +
                              resid[(size_t)grow * ND + gcol];
                    acc[nc][mt][nt][rr] = v;
                    s8[mt][rr] += v;
                    q8[mt][rr] += v * v;
                }
            }
    // 16-lane butterfly over lrow bits (stays within quad group)
#pragma unroll
    for (int mt = 0; mt < 2; ++mt)
#pragma unroll
        for (int rr = 0; rr < 4; ++rr)
#pragma unroll
            for (int off = 1; off <= 8; off <<= 1) {
                s8[mt][rr] += __shfl_xor(s8[mt][rr], off, 64);
                q8[mt][rr] += __shfl_xor(q8[mt][rr], off, 64);
            }
    // cross-wave reduce (4 waves hold the same 32 rows)
    if (lrow == 0) {
#pragma unroll
        for (int mt = 0; mt < 2; ++mt)
#pragma unroll
            for (int rr = 0; rr < 4; ++rr) {
                const int rl = mt * 16 + quad * 4 + rr;
                red[wv][rl][0] = s8[mt][rr];
                red[wv][rl][1] = q8[mt][rr];
            }
    }
    __syncthreads();
    float mu8[2][4], rs8[2][4];
#pragma unroll
    for (int mt = 0; mt < 2; ++mt)
#pragma unroll
        for (int rr = 0; rr < 4; ++rr) {
            const int rl = mt * 16 + quad * 4 + rr;
            const float s = red[0][rl][0] + red[1][rl][0] + red[2][rl][0] + red[3][rl][0];
            const float q = red[0][rl][1] + red[1][rl][1] + red[2][rl][1] + red[3][rl][1];
            const float mu = s * (1.0f / ND);
            const float var = q * (1.0f / ND) - mu * mu;
            mu8[mt][rr] = mu;
            rs8[mt][rr] = rsqrtf(var + 1e-5f);
        }
    // normalize + write out
#pragma unroll
    for (int nc = 0; nc < 4; ++nc)
#pragma unroll
        for (int mt = 0; mt < 2; ++mt)
#pragma unroll
            for (int nt = 0; nt < 4; ++nt) {
                const int gcol = nc * 256 + wv * 64 + nt * 16 + lrow;
                const float g = gamma[gcol], bt = beta[gcol];
#pragma unroll
                for (int rr = 0; rr < 4; ++rr) {
                    const int grow = row0 + mt * 16 + quad * 4 + rr;
                    out[(size_t)grow * ND + gcol] =
                        (acc[nc][mt][nt][rr] - mu8[mt][rr]) * rs8[mt][rr] * g + bt;
                }
            }
}

// ---------------------------------------------------------------------------
// stage2a: partial kk/ktv per (b,h,split). grid = (64, 8), 256 threads.
// Each block covers 512 tokens; each wave 128 tokens (4 iters of 32).
// Writes fp32 partial tile [64][128] (kk | ktv) to Part[bh*8+split].
// ---------------------------------------------------------------------------
__global__ __launch_bounds__(256) void stage2a_kernel(
    const u16* __restrict__ qkv,   // [16384][3072] bf16 (q|k|v)
    float* __restrict__ Part)      // [64*8][64*128] fp32
{
    __shared__ alignas(16) u16 sKt[4][64][40];   // per-wave K^T tile (pad 40)
    __shared__ alignas(16) u16 sVt[4][64][40];
    __shared__ float S[64][132];

    const int tid = threadIdx.x;
    const int wv = tid >> 6, lane = tid & 63;
    const int quad = lane >> 4, lrow = lane & 15;
    const int bh = blockIdx.x, split = blockIdx.y;
    const int b = bh >> 4, h = bh & 15;

    f32x4 akk[4][4] = {};
    f32x4 aktv[4][4] = {};
    const u16* kbase = qkv + ND + h * 64;
    const u16* vbase = qkv + 2 * ND + h * 64;
    const size_t tok0 = (size_t)b * NN;

    for (int it = 0; it < 4; ++it) {
        const int n0 = split * 512 + wv * 128 + it * 32;
#pragma unroll
        for (int pass = 0; pass < 4; ++pass) {
            int nl = pass * 8 + (lane >> 3);
            int d0 = (lane & 7) * 8;
            size_t roff = (tok0 + n0 + nl) * 3072 + d0;
            u16x8 kvv = *(const u16x8*)(kbase + roff);
            u16x8 vvv = *(const u16x8*)(vbase + roff);
#pragma unroll
            for (int j = 0; j < 8; ++j) {
                sKt[wv][d0 + j][nl] = kvv[j];
                sVt[wv][d0 + j][nl] = vvv[j];
            }
        }
        bf16x8 fK[4], fV[4];
#pragma unroll
        for (int t = 0; t < 4; ++t) {
            fK[t] = *(const bf16x8*)&sKt[wv][t * 16 + lrow][quad * 8];
            fV[t] = *(const bf16x8*)&sVt[wv][t * 16 + lrow][quad * 8];
        }
#pragma unroll
        for (int mt = 0; mt < 4; ++mt)
#pragma unroll
            for (int et = 0; et < 4; ++et) {
                akk[mt][et] = __builtin_amdgcn_mfma_f32_16x16x32_bf16(
                    fK[mt], fK[et], akk[mt][et], 0, 0, 0);
                aktv[mt][et] = __builtin_amdgcn_mfma_f32_16x16x32_bf16(
                    fK[mt], fV[et], aktv[mt][et], 0, 0, 0);
            }
    }

    // cross-wave reduce into S
    for (int w = 0; w < 4; ++w) {
        if (wv == w) {
#pragma unroll
            for (int mt = 0; mt < 4; ++mt)
#pragma unroll
                for (int et = 0; et < 4; ++et)
#pragma unroll
                    for (int r = 0; r < 4; ++r) {
                        int row = mt * 16 + quad * 4 + r;
                        int col = et * 16 + lrow;
                        if (w == 0) {
                            S[row][col] = akk[mt][et][r];
                            S[row][64 + col] = aktv[mt][et][r];
                        } else {
                            S[row][col] += akk[mt][et][r];
                            S[row][64 + col] += aktv[mt][et][r];
                        }
                    }
        }
        __syncthreads();
    }

    // coalesced fp32 write-out
    float* dst = Part + (size_t)(bh * 8 + split) * 8192;
#pragma unroll
    for (int c = 0; c < 8; ++c) {
        int idx = tid * 4 + c * 1024;
        int row = idx >> 7, col = idx & 127;
        float4 v = *(const float4*)&S[row][col];
        ((float4*)dst)[idx >> 2] = v;
    }
}

// ---------------------------------------------------------------------------
// stage2b: per (b,h): sum partials, +alpha*I, REGISTER-RESIDENT Gauss-Jordan
// wave-shuffle column softmax, M = Wo_h @ attn^T (MFMA). grid = 64.
// ---------------------------------------------------------------------------
__global__ __launch_bounds__(256) void stage2b_kernel(
    const float* __restrict__ Part,
    const u16* __restrict__ wb,    // [4096][1024] bf16, Wo rows at 3072
    const float* __restrict__ alpha,
    const float* __restrict__ temp,
    u16* __restrict__ Mout)        // [4][1024][1024] bf16
{
    __shared__ float S[64][132];
    __shared__ float colbuf[2][64];
    __shared__ alignas(16) u16 sAttn[64][72];

    const int tid = threadIdx.x;
    const int wv = tid >> 6, lane = tid & 63;   // row r = lane, colgroup = wv
    const int quad = lane >> 4, lrow = lane & 15;
    const int b = blockIdx.x >> 4, h = blockIdx.x & 15;

    // ---- reduce 8 partials into S (coalesced float4 reads) ----
    const float* Pb = Part + (size_t)blockIdx.x * 8 * 8192;
#pragma unroll
    for (int c = 0; c < 8; ++c) {
        int idx = tid * 4 + c * 1024;
        float4 a = ((const float4*)Pb)[idx >> 2];
#pragma unroll
        for (int s = 1; s < 8; ++s) {
            float4 t4 = ((const float4*)(Pb + (size_t)s * 8192))[idx >> 2];
            a.x += t4.x; a.y += t4.y; a.z += t4.z; a.w += t4.w;
        }
        int row = idx >> 7, col = idx & 127;
        *(float4*)&S[row][col] = a;
    }
    __syncthreads();

    // ---- load my 32 columns into registers; + alpha on diagonal ----
    const float aval = alpha[0];
    const int c0 = wv * 32;
    float R[32];
#pragma unroll
    for (int j = 0; j < 32; ++j) {
        R[j] = S[lane][c0 + j];
        if (c0 + j == lane) R[j] += aval;
    }
    if (wv == 0) colbuf[0][lane] = R[0];
    __syncthreads();

    // ---- Gauss-Jordan, registers + readlane (no pivoting: SPD dominant) ----
    float mydiag = 1.0f;
    for (int p = 0; p < 64; ++p) {
        const int cur = p & 1;
        float cv = colbuf[cur][lane];
        float pv = colbuf[cur][p];
        if (p == lane) mydiag = pv;
        float m = (lane == p) ? 0.0f : cv * __builtin_amdgcn_rcpf(pv);
#pragma unroll
        for (int j = 0; j < 32; ++j) {
            float rowv = __uint_as_float(
                __builtin_amdgcn_readlane(__float_as_uint(R[j]), p));
            R[j] -= m * rowv;
        }
        if (p < 63) {
            int pn = p + 1;
            if (wv == (pn >> 5)) colbuf[cur ^ 1][lane] = R[pn & 31];
        }
        __syncthreads();
    }

    // ---- right half: X = R/diag; column softmax over rows via shuffles ----
    if (wv >= 2) {
        const float idg = __builtin_amdgcn_rcpf(mydiag) * (1.0f / temp[0]);
#pragma unroll
        for (int j = 0; j < 32; ++j) {
            float xv = R[j] * idg;
            float mx = xv;
#pragma unroll
            for (int off = 32; off > 0; off >>= 1)
                mx = fmaxf(mx, __shfl_xor(mx, off, 64));
            float ev = __expf(xv - mx);
            float sum = ev;
#pragma unroll
            for (int off = 32; off > 0; off >>= 1)
                sum += __shfl_xor(sum, off, 64);
            sAttn[lane][(wv - 2) * 32 + j] = f2bf(ev * __builtin_amdgcn_rcpf(sum));
        }
    }
    __syncthreads();

    // ---- M_b[o][h*64+d] = sum_e Wo[o][h*64+e]*attn[d][e] via MFMA ----
    {
        bf16x8 fB[4][2];
#pragma unroll
        for (int nt = 0; nt < 4; ++nt)
#pragma unroll
            for (int ks = 0; ks < 2; ++ks)
                fB[nt][ks] = *(const bf16x8*)&sAttn[nt * 16 + lrow][ks * 32 + quad * 8];

        const u16* wo = wb + (size_t)3072 * ND + h * 64;
        u16* Mb = Mout + (size_t)b * ND * ND + h * 64;
        for (int i = 0; i < 16; ++i) {
            int mt = wv * 16 + i;
            int oA = mt * 16 + lrow;
            bf16x8 fA[2];
#pragma unroll
            for (int ks = 0; ks < 2; ++ks)
                fA[ks] = *(const bf16x8*)(wo + (size_t)oA * ND + ks * 32 + quad * 8);
#pragma unroll
            for (int nt = 0; nt < 4; ++nt) {
                f32x4 acc = {};
                acc = __builtin_amdgcn_mfma_f32_16x16x32_bf16(fA[0], fB[nt][0], acc, 0, 0, 0);
                acc = __builtin_amdgcn_mfma_f32_16x16x32_bf16(fA[1], fB[nt][1], acc, 0, 0, 0);
#pragma unroll
                for (int r = 0; r < 4; ++r) {
                    int o = mt * 16 + quad * 4 + r;
                    Mb[(size_t)o * ND + nt * 16 + lrow] = f2bf(acc[r]);
                }
            }
        }
    }
}

// ---------------------------------------------------------------------------
extern "C" void kernel_launch(void* const* d_in, const int* in_sizes, int n_in,
                              void* d_out, int out_size, void* d_ws, size_t ws_size,
                              hipStream_t stream)
{
    const float* x     = (const float*)d_in[0];
    const float* Wq    = (const float*)d_in[1];
    const float* Wk    = (const float*)d_in[2];
    const float* Wv    = (const float*)d_in[3];
    const float* Wo    = (const float*)d_in[4];
    const float* bo    = (const float*)d_in[5];
    const float* alpha = (const float*)d_in[6];
    const float* temp  = (const float*)d_in[7];
    const float* gamma = (const float*)d_in[8];
    const float* beta  = (const float*)d_in[9];

    char* ws = (char*)d_ws;
    u16* xb   = (u16*)(ws);                         // 33,554,432 B
    float* Part = (float*)(ws);                     // aliases xb (dead after gemm1); 16.8 MB
    u16* wb   = (u16*)(ws + 33554432);              //  8,388,608 B
    u16* qkv  = (u16*)(ws + 41943040);              // 100,663,296 B
    u16* Mb   = (u16*)(ws + 142606336);             //  8,388,608 B  (total 151 MB)
    float* out = (float*)d_out;

    prep_cast<<<dim3(4096), dim3(256), 0, stream>>>(x, Wq, Wk, Wv, Wo, xb, wb);

    // QKV: [16384 x 3072] = x_bf16 @ [Wq;Wk;Wv]^T   (256x128 tiles, 1536 blocks)
    gemm_bt<0><<<dim3(24, 64), dim3(256), 0, stream>>>(
        xb, 1024, wb, 1024, (void*)qkv, 3072, 1024,
        nullptr, nullptr, 1 << 30, (size_t)0);

    // stage2 split: partials across 512 blocks, then solve on 64 blocks
    stage2a_kernel<<<dim3(64, 8), dim3(256), 0, stream>>>(qkv, Part);
    stage2b_kernel<<<dim3(64), dim3(256), 0, stream>>>(Part, wb, alpha, temp, Mb);

    // fused: out = LN(q @ M_b^T + bo + x)   (32-row blocks, 512 total)
    gemm2_ln<<<dim3(512), dim3(256), 0, stream>>>(
        qkv, Mb, bo, x, gamma, beta, out);
}

// Round 6
// 383.341 us; speedup vs baseline: 1.1189x; 1.1189x over previous
//
#include <hip/hip_runtime.h>
#include <cstdint>
#include <cstddef>

typedef unsigned short u16;
typedef __bf16 bf16x8 __attribute__((ext_vector_type(8)));
typedef float f32x4 __attribute__((ext_vector_type(4)));
typedef u16 u16x8 __attribute__((ext_vector_type(8)));
typedef u16 u16x4 __attribute__((ext_vector_type(4)));

#define NB 4
#define NN 4096
#define ND 1024
#define NH 16
#define NTOK (NB * NN)   // 16384

__device__ __forceinline__ u16 f2bf(float f) {
    unsigned u = __float_as_uint(f);
    u += 0x7fffu + ((u >> 16) & 1u);
    return (u16)(u >> 16);
}

__device__ __forceinline__ void gload_lds16(const void* g, void* l) {
    __builtin_amdgcn_global_load_lds(
        (const __attribute__((address_space(1))) void*)g,
        (__attribute__((address_space(3))) void*)l, 16, 0, 0);
}

// ---------------------------------------------------------------------------
// prep: cast x (fp32->bf16) and Wq|Wk|Wv|Wo into one bf16 weight block
// ---------------------------------------------------------------------------
__global__ __launch_bounds__(256) void prep_cast(
    const float* __restrict__ x,
    const float* __restrict__ wq, const float* __restrict__ wk,
    const float* __restrict__ wv, const float* __restrict__ wo,
    u16* __restrict__ xb, u16* __restrict__ wb)
{
    const int n_x4 = (NTOK * ND) / 4;       // 4194304
    const int n_w4 = (ND * ND) / 4;         // 262144 per weight (pow2 -> shifts)
    const int total = n_x4 + 4 * n_w4;      // 5242880
    for (int i = blockIdx.x * blockDim.x + threadIdx.x; i < total;
         i += gridDim.x * blockDim.x) {
        float4 v;
        u16* dst;
        if (i < n_x4) {
            v = ((const float4*)x)[i];
            dst = xb + (size_t)i * 4;
        } else {
            int j = i - n_x4;
            int w = j / n_w4;
            int off = j - w * n_w4;
            const float* src = (w == 0) ? wq : (w == 1) ? wk : (w == 2) ? wv : wo;
            v = ((const float4*)src)[off];
            dst = wb + (size_t)j * 4;
        }
        u16x4 o;
        o[0] = f2bf(v.x); o[1] = f2bf(v.y); o[2] = f2bf(v.z); o[3] = f2bf(v.w);
        *(u16x4*)dst = o;
    }
}

// ---------------------------------------------------------------------------
// gemm_bt: C[m][n] = sum_k A[m][k]*B[n][k], bf16 MFMA.  (round-2 PROVEN: 996 TF)
// Block 256x128, BK=64, 4 waves, wave tile 128x64 (acc 128 VGPR).
// 2 barriers/K-step, unbroken 64-MFMA region (compiler schedules fine-grained
// lgkmcnt), 2 blocks/CU give implicit cross-block overlap. FAILED alternates
// (measured): r1 coarse phase-split 790 TF; r3 4-chunk ring 845 TF; r5 fused
// small-tile 242 TF. Do not re-introduce per-phase barriers/fences or small
// tiles; this 2-barrier structure + T1 is the measured optimum at HIP level.
// XCD-aware bijective block remap (T1): FETCH 144->94 MB measured.
// LDS rows are 8 chunks of 16B; chunk c of row r stored at c^(r&7) (bank
// swizzle). gload source lane-map permuted to match. Zero bank conflicts
// (measured SQ_LDS_BANK_CONFLICT=0).
// OUT_MODE 0: bf16 store; OUT_MODE 1: f32 store + bias[col] + resid[m][col]
// ---------------------------------------------------------------------------
template <int OUT_MODE>
__global__ __launch_bounds__(256, 2) void gemm_bt(
    const u16* __restrict__ A, int lda,
    const u16* __restrict__ Bw, int ldb,
    void* __restrict__ Cout, int ldc, int K,
    const float* __restrict__ bias, const float* __restrict__ resid,
    int rows_per_batch, size_t b_stride)
{
    __shared__ alignas(16) u16 lA[256 * 64];   // 32 KB
    __shared__ alignas(16) u16 lB[128 * 64];   // 16 KB

    const int tid = threadIdx.x;
    const int wv = tid >> 6, lane = tid & 63;
    const int quad = lane >> 4, lrow = lane & 15;

    // XCD-aware bijective remap (nwg % 8 == 0)
    const int orig = blockIdx.y * gridDim.x + blockIdx.x;
    const int cpx = (gridDim.x * gridDim.y) >> 3;
    const int wgid = (orig & 7) * cpx + (orig >> 3);
    const int bx = wgid % gridDim.x;
    const int by = wgid / gridDim.x;

    const int row0 = by * 256, col0 = bx * 128;
    const int wm = (wv >> 1) * 128, wn = (wv & 1) * 64;

    const u16* Bp = Bw + (b_stride ? (size_t)(row0 / rows_per_batch) * b_stride : 0);

    f32x4 acc[8][4] = {};

    const int srow = lane >> 3;                    // 0..7 (local row in 8-row seg)
    const int cswE = ((lane & 7) ^ srow) * 8;      // swizzled src col, elements

    for (int k0 = 0; k0 < K; k0 += 64) {
        __syncthreads();
#pragma unroll
        for (int i = 0; i < 8; ++i) {
            int rb = wv * 64 + i * 8;
            gload_lds16(A + (size_t)(row0 + rb + srow) * lda + k0 + cswE,
                        &lA[rb * 64]);
        }
#pragma unroll
        for (int i = 0; i < 4; ++i) {
            int rb = wv * 32 + i * 8;
            gload_lds16(Bp + (size_t)(col0 + rb + srow) * ldb + k0 + cswE,
                        &lB[rb * 64]);
        }
        __syncthreads();

#pragma unroll
        for (int kc = 0; kc < 2; ++kc) {
            const int ch = ((kc * 4 + quad) ^ (lrow & 7)) * 8;
            bf16x8 bfv[4];
#pragma unroll
            for (int t = 0; t < 4; ++t)
                bfv[t] = *(const bf16x8*)&lB[(wn + t * 16 + lrow) * 64 + ch];
#pragma unroll
            for (int mt = 0; mt < 8; ++mt) {
                bf16x8 af = *(const bf16x8*)&lA[(wm + mt * 16 + lrow) * 64 + ch];
#pragma unroll
                for (int nt = 0; nt < 4; ++nt)
                    acc[mt][nt] = __builtin_amdgcn_mfma_f32_16x16x32_bf16(
                        af, bfv[nt], acc[mt][nt], 0, 0, 0);
            }
        }
    }

    // epilogue; C/D layout: col = lane&15, row = quad*4 + reg
    float bvals[4];
    if (OUT_MODE == 1) {
#pragma unroll
        for (int nt = 0; nt < 4; ++nt)
            bvals[nt] = bias[col0 + wn + nt * 16 + lrow];
    }
#pragma unroll
    for (int mt = 0; mt < 8; ++mt)
#pragma unroll
        for (int nt = 0; nt < 4; ++nt)
#pragma unroll
            for (int r = 0; r < 4; ++r) {
                int grow = row0 + wm + mt * 16 + quad * 4 + r;
                int gcol = col0 + wn + nt * 16 + lrow;
                if (OUT_MODE == 0) {
                    ((u16*)Cout)[(size_t)grow * ldc + gcol] = f2bf(acc[mt][nt][r]);
                } else {
                    float vv = acc[mt][nt][r] + bvals[nt] +
                               resid[(size_t)grow * ldc + gcol];
                    ((float*)Cout)[(size_t)grow * ldc + gcol] = vv;
                }
            }
}

// ---------------------------------------------------------------------------
// stage2a: partial kk/ktv per (b,h,split). grid = (64, 8), 256 threads.
// Each block covers 512 tokens; each wave 128 tokens (4 iters of 32).
// Writes fp32 partial tile [64][128] (kk | ktv) to Part[bh*8+split].
// ---------------------------------------------------------------------------
__global__ __launch_bounds__(256) void stage2a_kernel(
    const u16* __restrict__ qkv,   // [16384][3072] bf16 (q|k|v)
    float* __restrict__ Part)      // [64*8][64*128] fp32
{
    __shared__ alignas(16) u16 sKt[4][64][40];   // per-wave K^T tile (pad 40)
    __shared__ alignas(16) u16 sVt[4][64][40];
    __shared__ float S[64][132];

    const int tid = threadIdx.x;
    const int wv = tid >> 6, lane = tid & 63;
    const int quad = lane >> 4, lrow = lane & 15;
    const int bh = blockIdx.x, split = blockIdx.y;
    const int b = bh >> 4, h = bh & 15;

    f32x4 akk[4][4] = {};
    f32x4 aktv[4][4] = {};
    const u16* kbase = qkv + ND + h * 64;
    const u16* vbase = qkv + 2 * ND + h * 64;
    const size_t tok0 = (size_t)b * NN;

    for (int it = 0; it < 4; ++it) {
        const int n0 = split * 512 + wv * 128 + it * 32;
#pragma unroll
        for (int pass = 0; pass < 4; ++pass) {
            int nl = pass * 8 + (lane >> 3);
            int d0 = (lane & 7) * 8;
            size_t roff = (tok0 + n0 + nl) * 3072 + d0;
            u16x8 kvv = *(const u16x8*)(kbase + roff);
            u16x8 vvv = *(const u16x8*)(vbase + roff);
#pragma unroll
            for (int j = 0; j < 8; ++j) {
                sKt[wv][d0 + j][nl] = kvv[j];
                sVt[wv][d0 + j][nl] = vvv[j];
            }
        }
        bf16x8 fK[4], fV[4];
#pragma unroll
        for (int t = 0; t < 4; ++t) {
            fK[t] = *(const bf16x8*)&sKt[wv][t * 16 + lrow][quad * 8];
            fV[t] = *(const bf16x8*)&sVt[wv][t * 16 + lrow][quad * 8];
        }
#pragma unroll
        for (int mt = 0; mt < 4; ++mt)
#pragma unroll
            for (int et = 0; et < 4; ++et) {
                akk[mt][et] = __builtin_amdgcn_mfma_f32_16x16x32_bf16(
                    fK[mt], fK[et], akk[mt][et], 0, 0, 0);
                aktv[mt][et] = __builtin_amdgcn_mfma_f32_16x16x32_bf16(
                    fK[mt], fV[et], aktv[mt][et], 0, 0, 0);
            }
    }

    // cross-wave reduce into S
    for (int w = 0; w < 4; ++w) {
        if (wv == w) {
#pragma unroll
            for (int mt = 0; mt < 4; ++mt)
#pragma unroll
                for (int et = 0; et < 4; ++et)
#pragma unroll
                    for (int r = 0; r < 4; ++r) {
                        int row = mt * 16 + quad * 4 + r;
                        int col = et * 16 + lrow;
                        if (w == 0) {
                            S[row][col] = akk[mt][et][r];
                            S[row][64 + col] = aktv[mt][et][r];
                        } else {
                            S[row][col] += akk[mt][et][r];
                            S[row][64 + col] += aktv[mt][et][r];
                        }
                    }
        }
        __syncthreads();
    }

    // coalesced fp32 write-out
    float* dst = Part + (size_t)(bh * 8 + split) * 8192;
#pragma unroll
    for (int c = 0; c < 8; ++c) {
        int idx = tid * 4 + c * 1024;
        int row = idx >> 7, col = idx & 127;
        float4 v = *(const float4*)&S[row][col];
        ((float4*)dst)[idx >> 2] = v;
    }
}

// ---------------------------------------------------------------------------
// stage2b: per (b,h): sum partials, +alpha*I, REGISTER-RESIDENT Gauss-Jordan
// wave-shuffle column softmax, M = Wo_h @ attn^T (MFMA). grid = 64.
// ---------------------------------------------------------------------------
__global__ __launch_bounds__(256) void stage2b_kernel(
    const float* __restrict__ Part,
    const u16* __restrict__ wb,    // [4096][1024] bf16, Wo rows at 3072
    const float* __restrict__ alpha,
    const float* __restrict__ temp,
    u16* __restrict__ Mout)        // [4][1024][1024] bf16
{
    __shared__ float S[64][132];
    __shared__ float colbuf[2][64];
    __shared__ alignas(16) u16 sAttn[64][72];

    const int tid = threadIdx.x;
    const int wv = tid >> 6, lane = tid & 63;   // row r = lane, colgroup = wv
    const int quad = lane >> 4, lrow = lane & 15;
    const int b = blockIdx.x >> 4, h = blockIdx.x & 15;

    // ---- reduce 8 partials into S (coalesced float4 reads) ----
    const float* Pb = Part + (size_t)blockIdx.x * 8 * 8192;
#pragma unroll
    for (int c = 0; c < 8; ++c) {
        int idx = tid * 4 + c * 1024;
        float4 a = ((const float4*)Pb)[idx >> 2];
#pragma unroll
        for (int s = 1; s < 8; ++s) {
            float4 t4 = ((const float4*)(Pb + (size_t)s * 8192))[idx >> 2];
            a.x += t4.x; a.y += t4.y; a.z += t4.z; a.w += t4.w;
        }
        int row = idx >> 7, col = idx & 127;
        *(float4*)&S[row][col] = a;
    }
    __syncthreads();

    // ---- load my 32 columns into registers; + alpha on diagonal ----
    const float aval = alpha[0];
    const int c0 = wv * 32;
    float R[32];
#pragma unroll
    for (int j = 0; j < 32; ++j) {
        R[j] = S[lane][c0 + j];
        if (c0 + j == lane) R[j] += aval;
    }
    if (wv == 0) colbuf[0][lane] = R[0];
    __syncthreads();

    // ---- Gauss-Jordan, registers + readlane (no pivoting: SPD dominant) ----
    float mydiag = 1.0f;
    for (int p = 0; p < 64; ++p) {
        const int cur = p & 1;
        float cv = colbuf[cur][lane];
        float pv = colbuf[cur][p];
        if (p == lane) mydiag = pv;
        float m = (lane == p) ? 0.0f : cv * __builtin_amdgcn_rcpf(pv);
#pragma unroll
        for (int j = 0; j < 32; ++j) {
            float rowv = __uint_as_float(
                __builtin_amdgcn_readlane(__float_as_uint(R[j]), p));
            R[j] -= m * rowv;
        }
        if (p < 63) {
            int pn = p + 1;
            if (wv == (pn >> 5)) colbuf[cur ^ 1][lane] = R[pn & 31];
        }
        __syncthreads();
    }

    // ---- right half: X = R/diag; column softmax over rows via shuffles ----
    if (wv >= 2) {
        const float idg = __builtin_amdgcn_rcpf(mydiag) * (1.0f / temp[0]);
#pragma unroll
        for (int j = 0; j < 32; ++j) {
            float xv = R[j] * idg;
            float mx = xv;
#pragma unroll
            for (int off = 32; off > 0; off >>= 1)
                mx = fmaxf(mx, __shfl_xor(mx, off, 64));
            float ev = __expf(xv - mx);
            float sum = ev;
#pragma unroll
            for (int off = 32; off > 0; off >>= 1)
                sum += __shfl_xor(sum, off, 64);
            sAttn[lane][(wv - 2) * 32 + j] = f2bf(ev * __builtin_amdgcn_rcpf(sum));
        }
    }
    __syncthreads();

    // ---- M_b[o][h*64+d] = sum_e Wo[o][h*64+e]*attn[d][e] via MFMA ----
    {
        bf16x8 fB[4][2];
#pragma unroll
        for (int nt = 0; nt < 4; ++nt)
#pragma unroll
            for (int ks = 0; ks < 2; ++ks)
                fB[nt][ks] = *(const bf16x8*)&sAttn[nt * 16 + lrow][ks * 32 + quad * 8];

        const u16* wo = wb + (size_t)3072 * ND + h * 64;
        u16* Mb = Mout + (size_t)b * ND * ND + h * 64;
        for (int i = 0; i < 16; ++i) {
            int mt = wv * 16 + i;
            int oA = mt * 16 + lrow;
            bf16x8 fA[2];
#pragma unroll
            for (int ks = 0; ks < 2; ++ks)
                fA[ks] = *(const bf16x8*)(wo + (size_t)oA * ND + ks * 32 + quad * 8);
#pragma unroll
            for (int nt = 0; nt < 4; ++nt) {
                f32x4 acc = {};
                acc = __builtin_amdgcn_mfma_f32_16x16x32_bf16(fA[0], fB[nt][0], acc, 0, 0, 0);
                acc = __builtin_amdgcn_mfma_f32_16x16x32_bf16(fA[1], fB[nt][1], acc, 0, 0, 0);
#pragma unroll
                for (int r = 0; r < 4; ++r) {
                    int o = mt * 16 + quad * 4 + r;
                    Mb[(size_t)o * ND + nt * 16 + lrow] = f2bf(acc[r]);
                }
            }
        }
    }
}

// ---------------------------------------------------------------------------
// layernorm: one WAVE per row (4 rows/block, 4096 blocks). Each lane holds
// 16 row-elements (4x float4) in registers; pure 6-level shfl_xor reduce,
// no LDS, no barriers. Same f32 math as before (reduction order change is
// ~1e-6 relative -- tolerance-irrelevant).
// ---------------------------------------------------------------------------
__global__ __launch_bounds__(256) void ln_kernel(
    const float* __restrict__ y, const float* __restrict__ gamma,
    const float* __restrict__ beta, float* __restrict__ out)
{
    const int wv = threadIdx.x >> 6, lane = threadIdx.x & 63;
    const int row = blockIdx.x * 4 + wv;
    const float* yr = y + (size_t)row * ND;
    float4 v[4];
    float s = 0.f, q = 0.f;
#pragma unroll
    for (int i = 0; i < 4; ++i) {
        v[i] = ((const float4*)yr)[i * 64 + lane];
        s += v[i].x + v[i].y + v[i].z + v[i].w;
        q += v[i].x * v[i].x + v[i].y * v[i].y + v[i].z * v[i].z + v[i].w * v[i].w;
    }
#pragma unroll
    for (int off = 32; off > 0; off >>= 1) {
        s += __shfl_xor(s, off, 64);
        q += __shfl_xor(q, off, 64);
    }
    const float mu = s * (1.0f / ND);
    const float var = q * (1.0f / ND) - mu * mu;
    const float rs = rsqrtf(var + 1e-5f);
    float* outr = out + (size_t)row * ND;
#pragma unroll
    for (int i = 0; i < 4; ++i) {
        const float4 g = ((const float4*)gamma)[i * 64 + lane];
        const float4 bt = ((const float4*)beta)[i * 64 + lane];
        float4 o;
        o.x = (v[i].x - mu) * rs * g.x + bt.x;
        o.y = (v[i].y - mu) * rs * g.y + bt.y;
        o.z = (v[i].z - mu) * rs * g.z + bt.z;
        o.w = (v[i].w - mu) * rs * g.w + bt.w;
        ((float4*)outr)[i * 64 + lane] = o;
    }
}

// ---------------------------------------------------------------------------
extern "C" void kernel_launch(void* const* d_in, const int* in_sizes, int n_in,
                              void* d_out, int out_size, void* d_ws, size_t ws_size,
                              hipStream_t stream)
{
    const float* x     = (const float*)d_in[0];
    const float* Wq    = (const float*)d_in[1];
    const float* Wk    = (const float*)d_in[2];
    const float* Wv    = (const float*)d_in[3];
    const float* Wo    = (const float*)d_in[4];
    const float* bo    = (const float*)d_in[5];
    const float* alpha = (const float*)d_in[6];
    const float* temp  = (const float*)d_in[7];
    const float* gamma = (const float*)d_in[8];
    const float* beta  = (const float*)d_in[9];

    char* ws = (char*)d_ws;
    u16* xb   = (u16*)(ws);                         // 33,554,432 B
    float* Part = (float*)(ws);                     // aliases xb (dead after gemm1); 16.8 MB
    u16* wb   = (u16*)(ws + 33554432);              //  8,388,608 B
    u16* qkv  = (u16*)(ws + 41943040);              // 100,663,296 B
    u16* Mb   = (u16*)(ws + 142606336);             //  8,388,608 B
    float* y  = (float*)(ws + 150994944);           // 67,108,864 B  (total 208 MB)
    float* out = (float*)d_out;

    prep_cast<<<dim3(4096), dim3(256), 0, stream>>>(x, Wq, Wk, Wv, Wo, xb, wb);

    // QKV: [16384 x 3072] = x_bf16 @ [Wq;Wk;Wv]^T   (256x128 tiles, 1536 blocks)
    gemm_bt<0><<<dim3(24, 64), dim3(256), 0, stream>>>(
        xb, 1024, wb, 1024, (void*)qkv, 3072, 1024,
        nullptr, nullptr, 1 << 30, (size_t)0);

    // stage2 split: partials across 512 blocks, then solve on 64 blocks
    stage2a_kernel<<<dim3(64, 8), dim3(256), 0, stream>>>(qkv, Part);
    stage2b_kernel<<<dim3(64), dim3(256), 0, stream>>>(Part, wb, alpha, temp, Mb);

    // y = q @ M_b^T + bo + x   (per-batch weights; 256 rows never straddle batch)
    gemm_bt<1><<<dim3(8, 64), dim3(256), 0, stream>>>(
        qkv, 3072, Mb, 1024, (void*)y, 1024, 1024,
        bo, x, 4096, (size_t)(1024 * 1024));

    ln_kernel<<<dim3(4096), dim3(256), 0, stream>>>(y, gamma, beta, out);
}

// Round 7
// 375.014 us; speedup vs baseline: 1.1438x; 1.0222x over previous
//
#include <hip/hip_runtime.h>
#include <cstdint>
#include <cstddef>

typedef unsigned short u16;
typedef __bf16 bf16x8 __attribute__((ext_vector_type(8)));
typedef float f32x4 __attribute__((ext_vector_type(4)));
typedef u16 u16x8 __attribute__((ext_vector_type(8)));
typedef u16 u16x4 __attribute__((ext_vector_type(4)));

#define NB 4
#define NN 4096
#define ND 1024
#define NH 16
#define NTOK (NB * NN)   // 16384

__device__ __forceinline__ u16 f2bf(float f) {
    unsigned u = __float_as_uint(f);
    u += 0x7fffu + ((u >> 16) & 1u);
    return (u16)(u >> 16);
}

__device__ __forceinline__ void gload_lds16(const void* g, void* l) {
    __builtin_amdgcn_global_load_lds(
        (const __attribute__((address_space(1))) void*)g,
        (__attribute__((address_space(3))) void*)l, 16, 0, 0);
}

// ---------------------------------------------------------------------------
// prep: cast x (fp32->bf16) and Wq|Wk|Wv|Wo into one bf16 weight block
// ---------------------------------------------------------------------------
__global__ __launch_bounds__(256) void prep_cast(
    const float* __restrict__ x,
    const float* __restrict__ wq, const float* __restrict__ wk,
    const float* __restrict__ wv, const float* __restrict__ wo,
    u16* __restrict__ xb, u16* __restrict__ wb)
{
    const int n_x4 = (NTOK * ND) / 4;       // 4194304
    const int n_w4 = (ND * ND) / 4;         // 262144 per weight (pow2 -> shifts)
    const int total = n_x4 + 4 * n_w4;      // 5242880
    for (int i = blockIdx.x * blockDim.x + threadIdx.x; i < total;
         i += gridDim.x * blockDim.x) {
        float4 v;
        u16* dst;
        if (i < n_x4) {
            v = ((const float4*)x)[i];
            dst = xb + (size_t)i * 4;
        } else {
            int j = i - n_x4;
            int w = j / n_w4;
            int off = j - w * n_w4;
            const float* src = (w == 0) ? wq : (w == 1) ? wk : (w == 2) ? wv : wo;
            v = ((const float4*)src)[off];
            dst = wb + (size_t)j * 4;
        }
        u16x4 o;
        o[0] = f2bf(v.x); o[1] = f2bf(v.y); o[2] = f2bf(v.z); o[3] = f2bf(v.w);
        *(u16x4*)dst = o;
    }
}

// ---------------------------------------------------------------------------
// gemm_bt: C[m][n] = sum_k A[m][k]*B[n][k], bf16 MFMA.  (PROVEN: 996 TF)
// Block 256x128, BK=64, 4 waves, wave tile 128x64 (acc 128 VGPR).
// 2 barriers/K-step, unbroken 64-MFMA region (compiler schedules fine-grained
// lgkmcnt), 2 blocks/CU give implicit cross-block overlap. FAILED alternates
// (measured): r1 coarse phase-split 790 TF; r3 4-chunk ring 845 TF; r5 fused
// small-tile 242 TF. Do not re-introduce per-phase barriers/fences or small
// tiles; this 2-barrier structure + T1 is the measured optimum at HIP level.
// XCD-aware bijective block remap (T1): FETCH 144->94 MB measured.
// LDS rows are 8 chunks of 16B; chunk c of row r stored at c^(r&7) (bank
// swizzle). gload source lane-map permuted to match. Zero bank conflicts
// (measured SQ_LDS_BANK_CONFLICT=0).
// OUT_MODE 0: bf16 store; OUT_MODE 1: f32 store + bias[col] + resid[m][col]
// ---------------------------------------------------------------------------
template <int OUT_MODE>
__global__ __launch_bounds__(256, 2) void gemm_bt(
    const u16* __restrict__ A, int lda,
    const u16* __restrict__ Bw, int ldb,
    void* __restrict__ Cout, int ldc, int K,
    const float* __restrict__ bias, const float* __restrict__ resid,
    int rows_per_batch, size_t b_stride)
{
    __shared__ alignas(16) u16 lA[256 * 64];   // 32 KB
    __shared__ alignas(16) u16 lB[128 * 64];   // 16 KB

    const int tid = threadIdx.x;
    const int wv = tid >> 6, lane = tid & 63;
    const int quad = lane >> 4, lrow = lane & 15;

    // XCD-aware bijective remap (nwg % 8 == 0)
    const int orig = blockIdx.y * gridDim.x + blockIdx.x;
    const int cpx = (gridDim.x * gridDim.y) >> 3;
    const int wgid = (orig & 7) * cpx + (orig >> 3);
    const int bx = wgid % gridDim.x;
    const int by = wgid / gridDim.x;

    const int row0 = by * 256, col0 = bx * 128;
    const int wm = (wv >> 1) * 128, wn = (wv & 1) * 64;

    const u16* Bp = Bw + (b_stride ? (size_t)(row0 / rows_per_batch) * b_stride : 0);

    f32x4 acc[8][4] = {};

    const int srow = lane >> 3;                    // 0..7 (local row in 8-row seg)
    const int cswE = ((lane & 7) ^ srow) * 8;      // swizzled src col, elements

    for (int k0 = 0; k0 < K; k0 += 64) {
        __syncthreads();
#pragma unroll
        for (int i = 0; i < 8; ++i) {
            int rb = wv * 64 + i * 8;
            gload_lds16(A + (size_t)(row0 + rb + srow) * lda + k0 + cswE,
                        &lA[rb * 64]);
        }
#pragma unroll
        for (int i = 0; i < 4; ++i) {
            int rb = wv * 32 + i * 8;
            gload_lds16(Bp + (size_t)(col0 + rb + srow) * ldb + k0 + cswE,
                        &lB[rb * 64]);
        }
        __syncthreads();

#pragma unroll
        for (int kc = 0; kc < 2; ++kc) {
            const int ch = ((kc * 4 + quad) ^ (lrow & 7)) * 8;
            bf16x8 bfv[4];
#pragma unroll
            for (int t = 0; t < 4; ++t)
                bfv[t] = *(const bf16x8*)&lB[(wn + t * 16 + lrow) * 64 + ch];
#pragma unroll
            for (int mt = 0; mt < 8; ++mt) {
                bf16x8 af = *(const bf16x8*)&lA[(wm + mt * 16 + lrow) * 64 + ch];
#pragma unroll
                for (int nt = 0; nt < 4; ++nt)
                    acc[mt][nt] = __builtin_amdgcn_mfma_f32_16x16x32_bf16(
                        af, bfv[nt], acc[mt][nt], 0, 0, 0);
            }
        }
    }

    // epilogue; C/D layout: col = lane&15, row = quad*4 + reg
    float bvals[4];
    if (OUT_MODE == 1) {
#pragma unroll
        for (int nt = 0; nt < 4; ++nt)
            bvals[nt] = bias[col0 + wn + nt * 16 + lrow];
    }
#pragma unroll
    for (int mt = 0; mt < 8; ++mt)
#pragma unroll
        for (int nt = 0; nt < 4; ++nt)
#pragma unroll
            for (int r = 0; r < 4; ++r) {
                int grow = row0 + wm + mt * 16 + quad * 4 + r;
                int gcol = col0 + wn + nt * 16 + lrow;
                if (OUT_MODE == 0) {
                    ((u16*)Cout)[(size_t)grow * ldc + gcol] = f2bf(acc[mt][nt][r]);
                } else {
                    float vv = acc[mt][nt][r] + bvals[nt] +
                               resid[(size_t)grow * ldc + gcol];
                    ((float*)Cout)[(size_t)grow * ldc + gcol] = vv;
                }
            }
}

// ---------------------------------------------------------------------------
// stage2a: partial kk/ktv per (b,h,split). grid = (64, 8), 256 threads.
// Each block covers 512 tokens; each wave 128 tokens (4 iters of 32).
// Writes fp32 partial tile [64][128] (kk | ktv) to Part[bh*8+split].
// LDS transpose SWIZZLE (this round): element (d, tk) stored at token-granule
// (tk>>3) ^ ((d>>3)&3) within the padded [64][40] tile. Before: the 8 d-groups
// (stride 8 rows = 160 words = 0 mod 32) all hit the same 4 banks -> 16-way
// conflict on every u16 store. After: 4-way (1.58x, m136). Reads use the same
// XOR at granule level -> identical fragment data, 16B-aligned.
// ---------------------------------------------------------------------------
__global__ __launch_bounds__(256) void stage2a_kernel(
    const u16* __restrict__ qkv,   // [16384][3072] bf16 (q|k|v)
    float* __restrict__ Part)      // [64*8][64*128] fp32
{
    __shared__ alignas(16) u16 sKt[4][64][40];   // per-wave K^T tile (pad 40)
    __shared__ alignas(16) u16 sVt[4][64][40];
    __shared__ float S[64][132];

    const int tid = threadIdx.x;
    const int wv = tid >> 6, lane = tid & 63;
    const int quad = lane >> 4, lrow = lane & 15;
    const int bh = blockIdx.x, split = blockIdx.y;
    const int b = bh >> 4, h = bh & 15;

    f32x4 akk[4][4] = {};
    f32x4 aktv[4][4] = {};
    const u16* kbase = qkv + ND + h * 64;
    const u16* vbase = qkv + 2 * ND + h * 64;
    const size_t tok0 = (size_t)b * NN;

    for (int it = 0; it < 4; ++it) {
        const int n0 = split * 512 + wv * 128 + it * 32;
        const int wi = lane >> 3;          // within-granule token index
        const int a  = lane & 7;           // d-group (d0 = a*8)
#pragma unroll
        for (int pass = 0; pass < 4; ++pass) {
            int nl = pass * 8 + wi;
            int d0 = a * 8;
            size_t roff = (tok0 + n0 + nl) * 3072 + d0;
            u16x8 kvv = *(const u16x8*)(kbase + roff);
            u16x8 vvv = *(const u16x8*)(vbase + roff);
#pragma unroll
            for (int j = 0; j < 8; ++j) {
                // d = d0 + j -> (d>>3)&3 = a&3 (swizzle key)
                int colp = (((pass ^ (a & 3)) << 3) + wi);
                sKt[wv][d0 + j][colp] = kvv[j];
                sVt[wv][d0 + j][colp] = vvv[j];
            }
        }
        bf16x8 fK[4], fV[4];
#pragma unroll
        for (int t = 0; t < 4; ++t) {
            // d = t*16+lrow -> (d>>3)&3 = (2t + (lrow>>3)) & 3
            const int g = ((quad ^ ((2 * t + (lrow >> 3)) & 3)) << 3);
            fK[t] = *(const bf16x8*)&sKt[wv][t * 16 + lrow][g];
            fV[t] = *(const bf16x8*)&sVt[wv][t * 16 + lrow][g];
        }
#pragma unroll
        for (int mt = 0; mt < 4; ++mt)
#pragma unroll
            for (int et = 0; et < 4; ++et) {
                akk[mt][et] = __builtin_amdgcn_mfma_f32_16x16x32_bf16(
                    fK[mt], fK[et], akk[mt][et], 0, 0, 0);
                aktv[mt][et] = __builtin_amdgcn_mfma_f32_16x16x32_bf16(
                    fK[mt], fV[et], aktv[mt][et], 0, 0, 0);
            }
    }

    // cross-wave reduce into S
    for (int w = 0; w < 4; ++w) {
        if (wv == w) {
#pragma unroll
            for (int mt = 0; mt < 4; ++mt)
#pragma unroll
                for (int et = 0; et < 4; ++et)
#pragma unroll
                    for (int r = 0; r < 4; ++r) {
                        int row = mt * 16 + quad * 4 + r;
                        int col = et * 16 + lrow;
                        if (w == 0) {
                            S[row][col] = akk[mt][et][r];
                            S[row][64 + col] = aktv[mt][et][r];
                        } else {
                            S[row][col] += akk[mt][et][r];
                            S[row][64 + col] += aktv[mt][et][r];
                        }
                    }
        }
        __syncthreads();
    }

    // coalesced fp32 write-out
    float* dst = Part + (size_t)(bh * 8 + split) * 8192;
#pragma unroll
    for (int c = 0; c < 8; ++c) {
        int idx = tid * 4 + c * 1024;
        int row = idx >> 7, col = idx & 127;
        float4 v = *(const float4*)&S[row][col];
        ((float4*)dst)[idx >> 2] = v;
    }
}

// ---------------------------------------------------------------------------
// stage2b: per (b,h): sum partials, +alpha*I, REGISTER-RESIDENT Gauss-Jordan,
// wave-shuffle column softmax, M = Wo_h @ attn^T (MFMA). grid = 64.
// THIS ROUND: 512 threads (8 waves). Each thread owns 16 cols (R[16]) ->
// readlane chain per pivot halves (16 vs 32); final MFMA loop 8 iters/wave.
// Identical math and per-element order.
// ---------------------------------------------------------------------------
__global__ __launch_bounds__(512) void stage2b_kernel(
    const float* __restrict__ Part,
    const u16* __restrict__ wb,    // [4096][1024] bf16, Wo rows at 3072
    const float* __restrict__ alpha,
    const float* __restrict__ temp,
    u16* __restrict__ Mout)        // [4][1024][1024] bf16
{
    __shared__ float S[64][132];
    __shared__ float colbuf[2][64];
    __shared__ alignas(16) u16 sAttn[64][72];

    const int tid = threadIdx.x;
    const int wv = tid >> 6, lane = tid & 63;   // row r = lane, colgroup = wv
    const int quad = lane >> 4, lrow = lane & 15;
    const int b = blockIdx.x >> 4, h = blockIdx.x & 15;

    // ---- reduce 8 partials into S (coalesced float4 reads, 512 threads) ----
    const float* Pb = Part + (size_t)blockIdx.x * 8 * 8192;
#pragma unroll
    for (int c = 0; c < 4; ++c) {
        int idx = tid * 4 + c * 2048;
        float4 a = ((const float4*)Pb)[idx >> 2];
#pragma unroll
        for (int s = 1; s < 8; ++s) {
            float4 t4 = ((const float4*)(Pb + (size_t)s * 8192))[idx >> 2];
            a.x += t4.x; a.y += t4.y; a.z += t4.z; a.w += t4.w;
        }
        int row = idx >> 7, col = idx & 127;
        *(float4*)&S[row][col] = a;
    }
    __syncthreads();

    // ---- load my 16 columns into registers; + alpha on diagonal ----
    const float aval = alpha[0];
    const int c0 = wv * 16;
    float R[16];
#pragma unroll
    for (int j = 0; j < 16; ++j) {
        R[j] = S[lane][c0 + j];
        if (c0 + j == lane) R[j] += aval;
    }
    if (wv == 0) colbuf[0][lane] = R[0];
    __syncthreads();

    // ---- Gauss-Jordan, registers + readlane (no pivoting: SPD dominant) ----
    float mydiag = 1.0f;
    for (int p = 0; p < 64; ++p) {
        const int cur = p & 1;
        float cv = colbuf[cur][lane];
        float pv = colbuf[cur][p];
        if (p == lane) mydiag = pv;
        float m = (lane == p) ? 0.0f : cv * __builtin_amdgcn_rcpf(pv);
#pragma unroll
        for (int j = 0; j < 16; ++j) {
            float rowv = __uint_as_float(
                __builtin_amdgcn_readlane(__float_as_uint(R[j]), p));
            R[j] -= m * rowv;
        }
        if (p < 63) {
            int pn = p + 1;
            if (wv == (pn >> 4)) colbuf[cur ^ 1][lane] = R[pn & 15];
        }
        __syncthreads();
    }

    // ---- right half: X = R/diag; column softmax over rows via shuffles ----
    if (wv >= 4) {
        const float idg = __builtin_amdgcn_rcpf(mydiag) * (1.0f / temp[0]);
#pragma unroll
        for (int j = 0; j < 16; ++j) {
            float xv = R[j] * idg;
            float mx = xv;
#pragma unroll
            for (int off = 32; off > 0; off >>= 1)
                mx = fmaxf(mx, __shfl_xor(mx, off, 64));
            float ev = __expf(xv - mx);
            float sum = ev;
#pragma unroll
            for (int off = 32; off > 0; off >>= 1)
                sum += __shfl_xor(sum, off, 64);
            sAttn[lane][(wv - 4) * 16 + j] = f2bf(ev * __builtin_amdgcn_rcpf(sum));
        }
    }
    __syncthreads();

    // ---- M_b[o][h*64+d] = sum_e Wo[o][h*64+e]*attn[d][e] via MFMA ----
    {
        bf16x8 fB[4][2];
#pragma unroll
        for (int nt = 0; nt < 4; ++nt)
#pragma unroll
            for (int ks = 0; ks < 2; ++ks)
                fB[nt][ks] = *(const bf16x8*)&sAttn[nt * 16 + lrow][ks * 32 + quad * 8];

        const u16* wo = wb + (size_t)3072 * ND + h * 64;
        u16* Mb = Mout + (size_t)b * ND * ND + h * 64;
        for (int i = 0; i < 8; ++i) {
            int mt = wv * 8 + i;
            int oA = mt * 16 + lrow;
            bf16x8 fA[2];
#pragma unroll
            for (int ks = 0; ks < 2; ++ks)
                fA[ks] = *(const bf16x8*)(wo + (size_t)oA * ND + ks * 32 + quad * 8);
#pragma unroll
            for (int nt = 0; nt < 4; ++nt) {
                f32x4 acc = {};
                acc = __builtin_amdgcn_mfma_f32_16x16x32_bf16(fA[0], fB[nt][0], acc, 0, 0, 0);
                acc = __builtin_amdgcn_mfma_f32_16x16x32_bf16(fA[1], fB[nt][1], acc, 0, 0, 0);
#pragma unroll
                for (int r = 0; r < 4; ++r) {
                    int o = mt * 16 + quad * 4 + r;
                    Mb[(size_t)o * ND + nt * 16 + lrow] = f2bf(acc[r]);
                }
            }
        }
    }
}

// ---------------------------------------------------------------------------
// layernorm: one WAVE per row (4 rows/block, 4096 blocks). Each lane holds
// 16 row-elements (4x float4) in registers; pure 6-level shfl_xor reduce,
// no LDS, no barriers.
// ---------------------------------------------------------------------------
__global__ __launch_bounds__(256) void ln_kernel(
    const float* __restrict__ y, const float* __restrict__ gamma,
    const float* __restrict__ beta, float* __restrict__ out)
{
    const int wv = threadIdx.x >> 6, lane = threadIdx.x & 63;
    const int row = blockIdx.x * 4 + wv;
    const float* yr = y + (size_t)row * ND;
    float4 v[4];
    float s = 0.f, q = 0.f;
#pragma unroll
    for (int i = 0; i < 4; ++i) {
        v[i] = ((const float4*)yr)[i * 64 + lane];
        s += v[i].x + v[i].y + v[i].z + v[i].w;
        q += v[i].x * v[i].x + v[i].y * v[i].y + v[i].z * v[i].z + v[i].w * v[i].w;
    }
#pragma unroll
    for (int off = 32; off > 0; off >>= 1) {
        s += __shfl_xor(s, off, 64);
        q += __shfl_xor(q, off, 64);
    }
    const float mu = s * (1.0f / ND);
    const float var = q * (1.0f / ND) - mu * mu;
    const float rs = rsqrtf(var + 1e-5f);
    float* outr = out + (size_t)row * ND;
#pragma unroll
    for (int i = 0; i < 4; ++i) {
        const float4 g = ((const float4*)gamma)[i * 64 + lane];
        const float4 bt = ((const float4*)beta)[i * 64 + lane];
        float4 o;
        o.x = (v[i].x - mu) * rs * g.x + bt.x;
        o.y = (v[i].y - mu) * rs * g.y + bt.y;
        o.z = (v[i].z - mu) * rs * g.z + bt.z;
        o.w = (v[i].w - mu) * rs * g.w + bt.w;
        ((float4*)outr)[i * 64 + lane] = o;
    }
}

// ---------------------------------------------------------------------------
extern "C" void kernel_launch(void* const* d_in, const int* in_sizes, int n_in,
                              void* d_out, int out_size, void* d_ws, size_t ws_size,
                              hipStream_t stream)
{
    const float* x     = (const float*)d_in[0];
    const float* Wq    = (const float*)d_in[1];
    const float* Wk    = (const float*)d_in[2];
    const float* Wv    = (const float*)d_in[3];
    const float* Wo    = (const float*)d_in[4];
    const float* bo    = (const float*)d_in[5];
    const float* alpha = (const float*)d_in[6];
    const float* temp  = (const float*)d_in[7];
    const float* gamma = (const float*)d_in[8];
    const float* beta  = (const float*)d_in[9];

    char* ws = (char*)d_ws;
    u16* xb   = (u16*)(ws);                         // 33,554,432 B
    float* Part = (float*)(ws);                     // aliases xb (dead after gemm1); 16.8 MB
    u16* wb   = (u16*)(ws + 33554432);              //  8,388,608 B
    u16* qkv  = (u16*)(ws + 41943040);              // 100,663,296 B
    u16* Mb   = (u16*)(ws + 142606336);             //  8,388,608 B
    float* y  = (float*)(ws + 150994944);           // 67,108,864 B  (total 208 MB)
    float* out = (float*)d_out;

    prep_cast<<<dim3(4096), dim3(256), 0, stream>>>(x, Wq, Wk, Wv, Wo, xb, wb);

    // QKV: [16384 x 3072] = x_bf16 @ [Wq;Wk;Wv]^T   (256x128 tiles, 1536 blocks)
    gemm_bt<0><<<dim3(24, 64), dim3(256), 0, stream>>>(
        xb, 1024, wb, 1024, (void*)qkv, 3072, 1024,
        nullptr, nullptr, 1 << 30, (size_t)0);

    // stage2 split: partials across 512 blocks, then solve on 64 blocks
    stage2a_kernel<<<dim3(64, 8), dim3(256), 0, stream>>>(qkv, Part);
    stage2b_kernel<<<dim3(64), dim3(512), 0, stream>>>(Part, wb, alpha, temp, Mb);

    // y = q @ M_b^T + bo + x   (per-batch weights; 256 rows never straddle batch)
    gemm_bt<1><<<dim3(8, 64), dim3(256), 0, stream>>>(
        qkv, 3072, Mb, 1024, (void*)y, 1024, 1024,
        bo, x, 4096, (size_t)(1024 * 1024));

    ln_kernel<<<dim3(4096), dim3(256), 0, stream>>>(y, gamma, beta, out);
}